// Round 5
// baseline (490.116 us; speedup 1.0000x reference)
//
#include <hip/hip_runtime.h>
#include <math.h>

#define NROWS 8192
#define DIM   64
#define KSEL  32
#define NQ    (NROWS - KSEL)   /* 8160 query rows */
#define P1LEN 512              /* pass-1 exact prefix */
#define CAP   1024             /* per-query candidate list capacity */

// ---------------------------------------------------------------------------
// Kernel A: row norms replicating XLA:CPU (LLVM-vectorized fused reduce):
//   VF=8 lanes, init 0, per-lane FMA chain, horizontal shuffle-tree
//   ((r0+r4)+(r2+r6)) + ((r1+r5)+(r3+r7)).   [validated bit-exact R8-R13]
// ---------------------------------------------------------------------------
__global__ void norms_kernel(const float* __restrict__ x, float* __restrict__ sq) {
    int j = blockIdx.x * blockDim.x + threadIdx.x;
    if (j >= NROWS) return;
    const float* xr = x + (size_t)j * DIM;
    float r[8];
#pragma unroll
    for (int u = 0; u < 8; ++u) r[u] = 0.0f;
#pragma unroll
    for (int i = 0; i < DIM; i += 8) {
#pragma unroll
        for (int u = 0; u < 8; ++u)
            r[u] = __fmaf_rn(xr[i + u], xr[i + u], r[u]);
    }
    const float s04 = __fadd_rn(r[0], r[4]);
    const float s26 = __fadd_rn(r[2], r[6]);
    const float s15 = __fadd_rn(r[1], r[5]);
    const float s37 = __fadd_rn(r[3], r[7]);
    sq[j] = __fadd_rn(__fadd_rn(s04, s26), __fadd_rn(s15, s37));
}

// ---------------------------------------------------------------------------
// Pass 1: ONE WAVE per query.  Exact top-32 over prefix [0, min(512, r)):
// 8 keys/lane in registers, 32 shuffle-only extract-min iterations.
// Writes the 32 keys to lists[qi][0..31], cnt[qi]=32, tau0[qi]=32nd key.
// Distance = bit-exact seq-FMA chain k=0..63 (validated).
// ---------------------------------------------------------------------------
__global__ __launch_bounds__(64)
void pass1_kernel(const float* __restrict__ x, const float* __restrict__ sq,
                  unsigned long long* __restrict__ tau0,
                  unsigned int* __restrict__ cnt,
                  unsigned long long* __restrict__ lists) {
    const int qi   = blockIdx.x;        // 0..8159
    const int r    = qi + KSEL;         // query row (wave-uniform)
    const int lane = threadIdx.x;
    const int P    = min(r, P1LEN);

    const float* qp  = x + (size_t)r * DIM;   // uniform -> scalar loads
    const float  sqr = sq[r];

    unsigned long long key[8];
#pragma unroll
    for (int s = 0; s < 8; ++s) {
        const int j = lane + (s << 6);
        unsigned long long k = ~0ull;
        if (j < P) {
            const float4* c4 = reinterpret_cast<const float4*>(x + (size_t)j * DIM);
            float acc = 0.0f;
#pragma unroll
            for (int i = 0; i < DIM / 4; ++i) {
                float4 v = c4[i];
                acc = __fmaf_rn(qp[4 * i + 0], v.x, acc);
                acc = __fmaf_rn(qp[4 * i + 1], v.y, acc);
                acc = __fmaf_rn(qp[4 * i + 2], v.z, acc);
                acc = __fmaf_rn(qp[4 * i + 3], v.w, acc);
            }
            const float dd =
                fmaxf(__fsub_rn(__fadd_rn(sqr, sq[j]), __fmul_rn(2.0f, acc)), 0.0f);
            k = ((unsigned long long)__float_as_uint(dd) << 32) | (unsigned)j;
        }
        key[s] = k;
    }

    unsigned long long pmin = ~0ull;
#pragma unroll
    for (int s = 0; s < 8; ++s) pmin = key[s] < pmin ? key[s] : pmin;

    unsigned long long g = ~0ull;
    for (int it = 0; it < KSEL; ++it) {
        unsigned long long v = pmin;
#pragma unroll
        for (int off = 32; off > 0; off >>= 1) {
            const unsigned long long o = __shfl_down(v, off, 64);
            v = o < v ? o : v;
        }
        g = __shfl(v, 0, 64);
        if (lane == 0) lists[(size_t)qi * CAP + it] = g;
        if (pmin == g) {            // unique winner (keys embed unique j)
#pragma unroll
            for (int s = 0; s < 8; ++s) if (key[s] == g) key[s] = ~0ull;
            pmin = ~0ull;
#pragma unroll
            for (int s = 0; s < 8; ++s) pmin = key[s] < pmin ? key[s] : pmin;
        }
    }
    if (lane == 0) { tau0[qi] = g; cnt[qi] = KSEL; }
}

// ---------------------------------------------------------------------------
// Pass 2 (v4): LDS-tiled fp32 GEMM filter over candidates [512, r).
// Tile = 128 queries x 128 candidates, 256 threads, 8x8 register micro-tile,
// K split in TWO 32-deep chunks (LDS = 32 KB).
// v3 POST-MORTEM: VGPR_Count=64 == the compiler capped the budget at 8
// waves/EU (512/8) with no launch_bounds hint and SPILLED the 64-entry
// accumulator set -> inner loop stalled on scratch (VALUBusy 13%, all pipes
// idle).  v4 fixes register pressure instead of structure:
//   * __launch_bounds__(256, 4)  -> VGPR cap 128 (4 waves/EU; LDS allows 5
//     blocks/CU, so effective residency 4 blocks = 16 waves/CU)
//   * staging regs are TRANSIENT (no prefetch held across a barrier)
//   * k-loop unroll 2 (32 operand regs, not 64)
//   peak live ~ 64 acc + 32 operands + ~20 addr ~= 116 <= 128  -> no spill.
// Accumulator chains still run k=0..63 ascending ACROSS chunks == validated
// bit-exact Eigen chain.  Epilogue unchanged (validated superset filter).
// ---------------------------------------------------------------------------
__global__ __launch_bounds__(256, 4)
void pass2_kernel(const float* __restrict__ x, const float* __restrict__ sq,
                  const unsigned long long* __restrict__ tau0,
                  unsigned int* __restrict__ cnt,
                  unsigned long long* __restrict__ lists) {
    const int qb   = blockIdx.x;                        // 0..63
    const int jb   = P1LEN + blockIdx.y * 128;          // candidate tile base
    const int r_hi = min(KSEL + (qb + 1) * 128, NROWS); // exclusive query cap
    if (jb >= r_hi) return;                             // uniform exit

    __shared__ float Qs[32 * 128];                      // Qs[kk*128 + ql]
    __shared__ float Cs[32 * 128];                      // Cs[kk*128 + cl]

    const int tid = threadIdx.x;
    const int row = tid >> 1;                           // 0..127
    const int kb  = (tid & 1) * 16;                     // k-offset within chunk
    const int rqs = min(KSEL + qb * 128 + row, NROWS - 1);
    const float* qrow = x + (size_t)rqs * DIM;
    const float* crow = x + (size_t)(jb + row) * DIM;

    const int tx = tid & 15;        // candidate group: cols {tx*4..+3, 64+tx*4..+3}
    const int ty = tid >> 4;        // query group:     rows {ty*4..+3, 64+ty*4..+3}

    float acc[8][8] = {{0.f}};      // acc[qa][cb], chains over k ascending

#pragma unroll
    for (int ch = 0; ch < 2; ++ch) {
        __syncthreads();            // previous chunk fully consumed
        {   // ---- global -> transient regs -> LDS transposed (L2-hot source;
            //      bank = row%32, 2 lanes/bank = free)
            const int koff = ch * 32 + kb;
            float4 vq[4], vc[4];
#pragma unroll
            for (int i = 0; i < 4; ++i) {
                vq[i] = *reinterpret_cast<const float4*>(qrow + koff + i * 4);
                vc[i] = *reinterpret_cast<const float4*>(crow + koff + i * 4);
            }
#pragma unroll
            for (int i = 0; i < 4; ++i) {
                const int d = kb + i * 4;
                Qs[(d + 0) * 128 + row] = vq[i].x; Qs[(d + 1) * 128 + row] = vq[i].y;
                Qs[(d + 2) * 128 + row] = vq[i].z; Qs[(d + 3) * 128 + row] = vq[i].w;
                Cs[(d + 0) * 128 + row] = vc[i].x; Cs[(d + 1) * 128 + row] = vc[i].y;
                Cs[(d + 2) * 128 + row] = vc[i].z; Cs[(d + 3) * 128 + row] = vc[i].w;
            }
        }
        __syncthreads();
        // ---- 32 k-steps: 4x ds_read_b128 + 64 FMA per lane per k
#pragma unroll 2
        for (int kk = 0; kk < 32; ++kk) {
            const float4 q0 = *reinterpret_cast<const float4*>(&Qs[kk * 128 + ty * 4]);
            const float4 q1 = *reinterpret_cast<const float4*>(&Qs[kk * 128 + 64 + ty * 4]);
            const float4 c0 = *reinterpret_cast<const float4*>(&Cs[kk * 128 + tx * 4]);
            const float4 c1 = *reinterpret_cast<const float4*>(&Cs[kk * 128 + 64 + tx * 4]);
            const float qv[8] = {q0.x, q0.y, q0.z, q0.w, q1.x, q1.y, q1.z, q1.w};
            const float cv[8] = {c0.x, c0.y, c0.z, c0.w, c1.x, c1.y, c1.z, c1.w};
#pragma unroll
            for (int a = 0; a < 8; ++a)
#pragma unroll
                for (int b = 0; b < 8; ++b)
                    acc[a][b] = __fmaf_rn(qv[a], cv[b], acc[a][b]);
        }
    }

#pragma unroll
    for (int a = 0; a < 8; ++a) {
        const int ql = ty * 4 + (a & 3) + ((a >> 2) << 6);
        const int rq = KSEL + qb * 128 + ql;
        if (rq >= NROWS) continue;
        const float    sqr = sq[rq];                    // L1-hot (128/block)
        const unsigned th  = (unsigned)(tau0[rq - KSEL] >> 32);
        const int      qi  = rq - KSEL;
#pragma unroll
        for (int b = 0; b < 8; ++b) {
            const int cl = tx * 4 + (b & 3) + ((b >> 2) << 6);
            const int j  = jb + cl;
            const float dd = fmaxf(
                __fsub_rn(__fadd_rn(sqr, sq[j]),
                          __fmul_rn(2.0f, acc[a][b])), 0.0f);
            const unsigned bits = __float_as_uint(dd);
            if (j < rq && bits <= th) {
                const unsigned s = atomicAdd(&cnt[qi], 1u);
                if (s < CAP)
                    lists[(size_t)qi * CAP + s] =
                        ((unsigned long long)bits << 32) | (unsigned)j;
            }
        }
    }
}

// ---------------------------------------------------------------------------
// Merge: ONE WAVE per query.  16 keys/lane in registers, 32 shuffle-only
// extract-min iterations.  u64-min = ascending (dist, index), low-index
// ties (validated top_k semantics).  List is a superset of the true top-32.
// ---------------------------------------------------------------------------
__global__ __launch_bounds__(64)
void merge_kernel(const unsigned long long* __restrict__ lists,
                  const unsigned int* __restrict__ cnt,
                  float* __restrict__ out_d, float* __restrict__ out_i) {
    const int qi   = blockIdx.x;     // 0..8159
    const int lane = threadIdx.x;
    const int ne   = min((int)cnt[qi], CAP);
    const unsigned long long* src = lists + (size_t)qi * CAP;

    unsigned long long k[16];
#pragma unroll
    for (int s = 0; s < 16; ++s) {
        const int idx = lane + (s << 6);
        k[s] = (idx < ne) ? src[idx] : ~0ull;
    }
    unsigned long long pmin = ~0ull;
#pragma unroll
    for (int s = 0; s < 16; ++s) pmin = k[s] < pmin ? k[s] : pmin;

    for (int it = 0; it < KSEL; ++it) {
        unsigned long long v = pmin;
#pragma unroll
        for (int off = 32; off > 0; off >>= 1) {
            const unsigned long long o = __shfl_down(v, off, 64);
            v = o < v ? o : v;
        }
        const unsigned long long g = __shfl(v, 0, 64);
        if (lane == 0) {
            out_d[(size_t)qi * KSEL + it] = __uint_as_float((unsigned)(g >> 32));
            out_i[(size_t)qi * KSEL + it] = (float)(unsigned)(g & 0xFFFFFFFFu);
        }
        if (pmin == g) {            // unique winner rescans its registers
#pragma unroll
            for (int s = 0; s < 16; ++s) if (k[s] == g) k[s] = ~0ull;
            pmin = ~0ull;
#pragma unroll
            for (int s = 0; s < 16; ++s) pmin = k[s] < pmin ? k[s] : pmin;
        }
    }
}

extern "C" void kernel_launch(void* const* d_in, const int* in_sizes, int n_in,
                              void* d_out, int out_size, void* d_ws, size_t ws_size,
                              hipStream_t stream) {
    const float* x = (const float*)d_in[0];    // anchor_x [8192, 64] fp32
    float* sq = (float*)d_ws;                                        // 32 KB
    unsigned long long* tau0 =
        (unsigned long long*)((char*)d_ws + 32768);                  // 64 KB
    unsigned int* cnt = (unsigned int*)((char*)d_ws + 98304);        // 32 KB
    unsigned long long* lists =
        (unsigned long long*)((char*)d_ws + 131072);                 // 66.8 MB
    float* out_d = (float*)d_out;              // [8160, 32] distances
    float* out_i = out_d + (size_t)NQ * KSEL;  // [8160, 32] indices (as fp32)

    norms_kernel<<<NROWS / 256, 256, 0, stream>>>(x, sq);
    pass1_kernel<<<NQ, 64, 0, stream>>>(x, sq, tau0, cnt, lists);
    dim3 g2(64, (NROWS - P1LEN) / 128);        // (query tile, candidate tile)
    pass2_kernel<<<g2, 256, 0, stream>>>(x, sq, tau0, cnt, lists);
    merge_kernel<<<NQ, 64, 0, stream>>>(lists, cnt, out_d, out_i);
}

// Round 6
// 434.841 us; speedup vs baseline: 1.1271x; 1.1271x over previous
//
#include <hip/hip_runtime.h>
#include <math.h>

#define NROWS 8192
#define DIM   64
#define KSEL  32
#define NQ    (NROWS - KSEL)   /* 8160 query rows */
#define P1LEN 512              /* pass-1 exact prefix */
#define CAP   1024             /* per-query candidate list capacity */

// ---------------------------------------------------------------------------
// Kernel A: row norms replicating XLA:CPU (LLVM-vectorized fused reduce):
//   VF=8 lanes, init 0, per-lane FMA chain, horizontal shuffle-tree
//   ((r0+r4)+(r2+r6)) + ((r1+r5)+(r3+r7)).   [validated bit-exact R8-R13]
// ---------------------------------------------------------------------------
__global__ void norms_kernel(const float* __restrict__ x, float* __restrict__ sq) {
    int j = blockIdx.x * blockDim.x + threadIdx.x;
    if (j >= NROWS) return;
    const float* xr = x + (size_t)j * DIM;
    float r[8];
#pragma unroll
    for (int u = 0; u < 8; ++u) r[u] = 0.0f;
#pragma unroll
    for (int i = 0; i < DIM; i += 8) {
#pragma unroll
        for (int u = 0; u < 8; ++u)
            r[u] = __fmaf_rn(xr[i + u], xr[i + u], r[u]);
    }
    const float s04 = __fadd_rn(r[0], r[4]);
    const float s26 = __fadd_rn(r[2], r[6]);
    const float s15 = __fadd_rn(r[1], r[5]);
    const float s37 = __fadd_rn(r[3], r[7]);
    sq[j] = __fadd_rn(__fadd_rn(s04, s26), __fadd_rn(s15, s37));
}

// ---------------------------------------------------------------------------
// Pass 1: ONE WAVE per query.  Exact top-32 over prefix [0, min(512, r)):
// 8 keys/lane in registers, 32 shuffle-only extract-min iterations.
// Writes the 32 keys to lists[qi][0..31], cnt[qi]=32, tau0[qi]=32nd key.
// Distance = bit-exact seq-FMA chain k=0..63 (validated).
// ---------------------------------------------------------------------------
__global__ __launch_bounds__(64)
void pass1_kernel(const float* __restrict__ x, const float* __restrict__ sq,
                  unsigned long long* __restrict__ tau0,
                  unsigned int* __restrict__ cnt,
                  unsigned long long* __restrict__ lists) {
    const int qi   = blockIdx.x;        // 0..8159
    const int r    = qi + KSEL;         // query row (wave-uniform)
    const int lane = threadIdx.x;
    const int P    = min(r, P1LEN);

    const float* qp  = x + (size_t)r * DIM;   // uniform -> scalar loads
    const float  sqr = sq[r];

    unsigned long long key[8];
#pragma unroll
    for (int s = 0; s < 8; ++s) {
        const int j = lane + (s << 6);
        unsigned long long k = ~0ull;
        if (j < P) {
            const float4* c4 = reinterpret_cast<const float4*>(x + (size_t)j * DIM);
            float acc = 0.0f;
#pragma unroll
            for (int i = 0; i < DIM / 4; ++i) {
                float4 v = c4[i];
                acc = __fmaf_rn(qp[4 * i + 0], v.x, acc);
                acc = __fmaf_rn(qp[4 * i + 1], v.y, acc);
                acc = __fmaf_rn(qp[4 * i + 2], v.z, acc);
                acc = __fmaf_rn(qp[4 * i + 3], v.w, acc);
            }
            const float dd =
                fmaxf(__fsub_rn(__fadd_rn(sqr, sq[j]), __fmul_rn(2.0f, acc)), 0.0f);
            k = ((unsigned long long)__float_as_uint(dd) << 32) | (unsigned)j;
        }
        key[s] = k;
    }

    unsigned long long pmin = ~0ull;
#pragma unroll
    for (int s = 0; s < 8; ++s) pmin = key[s] < pmin ? key[s] : pmin;

    unsigned long long g = ~0ull;
    for (int it = 0; it < KSEL; ++it) {
        unsigned long long v = pmin;
#pragma unroll
        for (int off = 32; off > 0; off >>= 1) {
            const unsigned long long o = __shfl_down(v, off, 64);
            v = o < v ? o : v;
        }
        g = __shfl(v, 0, 64);
        if (lane == 0) lists[(size_t)qi * CAP + it] = g;
        if (pmin == g) {            // unique winner (keys embed unique j)
#pragma unroll
            for (int s = 0; s < 8; ++s) if (key[s] == g) key[s] = ~0ull;
            pmin = ~0ull;
#pragma unroll
            for (int s = 0; s < 8; ++s) pmin = key[s] < pmin ? key[s] : pmin;
        }
    }
    if (lane == 0) { tau0[qi] = g; cnt[qi] = KSEL; }
}

// ---------------------------------------------------------------------------
// Pass 2 (v5): LDS-tiled fp32 GEMM filter over candidates [512, r).
// POST-MORTEM LADDER: v1 (4x4 micro, 52 VGPR, no spill) = 165us; v2 (8x8,
// 88 VGPR, no spill, 64KB LDS -> 2 blk/CU latency-bound) = 304us; v3/v4
// (8x8, VGPR capped 64/56 -> ACC SPILLED to scratch, all pipes idle) =
// 277/243us.  hipcc will not allocate >88 regs here; 64-acc micro-tiles
// are unallocatable.  v5 = 4x8 micro (32 accs), the largest tile in the
// PROVEN register envelope:
//   * tile 64q x 128c, 256 threads (tx=c-group 0..15, ty=q-group 0..15)
//   * LDS 48 KB (Qs[64k][64q] + Cs[64k][128c]) -> 3 blocks/CU, no K-split
//   * per k per lane: 1 Qs float4 (4 distinct addrs/wave -> broadcast,
//     near-free) + 2 Cs float4 (16 distinct addrs, 4-lane broadcast)
//     feeding 32 FMAs -> effective ~1.5 B/FMA with cheap broadcast side
//   * regs ~ 32 acc + 12 operand + ~15 addr ~= 60  -> no spill
// Accumulator chains run k=0..63 ascending == validated bit-exact Eigen
// chain.  Epilogue: accept bits(dist) <= tau_hi (superset), atomicAdd.
// ---------------------------------------------------------------------------
__global__ __launch_bounds__(256)
void pass2_kernel(const float* __restrict__ x, const float* __restrict__ sq,
                  const unsigned long long* __restrict__ tau0,
                  unsigned int* __restrict__ cnt,
                  unsigned long long* __restrict__ lists) {
    const int qb   = blockIdx.x;                        // 0..127 (64-q tiles)
    const int jb   = P1LEN + blockIdx.y * 128;          // candidate tile base
    const int r_hi = min(KSEL + (qb + 1) * 64, NROWS);  // exclusive query cap
    if (jb >= r_hi) return;                             // uniform exit

    __shared__ float Qs[DIM * 64];                      // Qs[k*64  + ql]
    __shared__ float Cs[DIM * 128];                     // Cs[k*128 + cl]

    const int tid = threadIdx.x;

    {   // ---- stage Q transposed: 64 rows, thread=(row=tid>>2, kq=(tid&3)*16)
        const int row = tid >> 2;                       // 0..63
        const int kq  = (tid & 3) * 16;
        const int rq  = min(KSEL + qb * 64 + row, NROWS - 1);
        const float4* s = reinterpret_cast<const float4*>(x + (size_t)rq * DIM + kq);
#pragma unroll
        for (int i = 0; i < 4; ++i) {
            float4 v = s[i];
            const int d = kq + i * 4;
            Qs[(d + 0) * 64 + row] = v.x; Qs[(d + 1) * 64 + row] = v.y;
            Qs[(d + 2) * 64 + row] = v.z; Qs[(d + 3) * 64 + row] = v.w;
        }
    }
    {   // ---- stage C transposed: 128 rows, thread=(row=tid>>1, kc=(tid&1)*32)
        //      write bank = row%32 -> 2 lanes/bank (free)
        const int row = tid >> 1;                       // 0..127
        const int kc  = (tid & 1) * 32;
        const float4* s = reinterpret_cast<const float4*>(x + (size_t)(jb + row) * DIM + kc);
#pragma unroll
        for (int i = 0; i < 8; ++i) {
            float4 v = s[i];
            const int d = kc + i * 4;
            Cs[(d + 0) * 128 + row] = v.x; Cs[(d + 1) * 128 + row] = v.y;
            Cs[(d + 2) * 128 + row] = v.z; Cs[(d + 3) * 128 + row] = v.w;
        }
    }
    __syncthreads();

    const int tx = tid & 15;        // candidate group: cols {tx*4..+3, 64+tx*4..+3}
    const int ty = tid >> 4;        // query group:     rows {ty*4..+3}

    float acc[4][8] = {{0.f}};      // acc[qa][cb], chains over k ascending
#pragma unroll 2
    for (int k = 0; k < DIM; ++k) {
        const float4 q0 = *reinterpret_cast<const float4*>(&Qs[k * 64 + ty * 4]);
        const float4 c0 = *reinterpret_cast<const float4*>(&Cs[k * 128 + tx * 4]);
        const float4 c1 = *reinterpret_cast<const float4*>(&Cs[k * 128 + 64 + tx * 4]);
        const float qv[4] = {q0.x, q0.y, q0.z, q0.w};
        const float cv[8] = {c0.x, c0.y, c0.z, c0.w, c1.x, c1.y, c1.z, c1.w};
#pragma unroll
        for (int a = 0; a < 4; ++a)
#pragma unroll
            for (int b = 0; b < 8; ++b)
                acc[a][b] = __fmaf_rn(qv[a], cv[b], acc[a][b]);
    }

#pragma unroll
    for (int a = 0; a < 4; ++a) {
        const int ql = ty * 4 + a;
        const int rq = KSEL + qb * 64 + ql;
        if (rq >= NROWS) continue;
        const float    sqr = sq[rq];                    // L1-hot (64/block)
        const unsigned th  = (unsigned)(tau0[rq - KSEL] >> 32);
        const int      qi  = rq - KSEL;
#pragma unroll
        for (int b = 0; b < 8; ++b) {
            const int cl = tx * 4 + (b & 3) + ((b >> 2) << 6);
            const int j  = jb + cl;
            const float dd = fmaxf(
                __fsub_rn(__fadd_rn(sqr, sq[j]),
                          __fmul_rn(2.0f, acc[a][b])), 0.0f);
            const unsigned bits = __float_as_uint(dd);
            if (j < rq && bits <= th) {
                const unsigned s = atomicAdd(&cnt[qi], 1u);
                if (s < CAP)
                    lists[(size_t)qi * CAP + s] =
                        ((unsigned long long)bits << 32) | (unsigned)j;
            }
        }
    }
}

// ---------------------------------------------------------------------------
// Merge: ONE WAVE per query.  16 keys/lane in registers, 32 shuffle-only
// extract-min iterations.  u64-min = ascending (dist, index), low-index
// ties (validated top_k semantics).  List is a superset of the true top-32.
// ---------------------------------------------------------------------------
__global__ __launch_bounds__(64)
void merge_kernel(const unsigned long long* __restrict__ lists,
                  const unsigned int* __restrict__ cnt,
                  float* __restrict__ out_d, float* __restrict__ out_i) {
    const int qi   = blockIdx.x;     // 0..8159
    const int lane = threadIdx.x;
    const int ne   = min((int)cnt[qi], CAP);
    const unsigned long long* src = lists + (size_t)qi * CAP;

    unsigned long long k[16];
#pragma unroll
    for (int s = 0; s < 16; ++s) {
        const int idx = lane + (s << 6);
        k[s] = (idx < ne) ? src[idx] : ~0ull;
    }
    unsigned long long pmin = ~0ull;
#pragma unroll
    for (int s = 0; s < 16; ++s) pmin = k[s] < pmin ? k[s] : pmin;

    for (int it = 0; it < KSEL; ++it) {
        unsigned long long v = pmin;
#pragma unroll
        for (int off = 32; off > 0; off >>= 1) {
            const unsigned long long o = __shfl_down(v, off, 64);
            v = o < v ? o : v;
        }
        const unsigned long long g = __shfl(v, 0, 64);
        if (lane == 0) {
            out_d[(size_t)qi * KSEL + it] = __uint_as_float((unsigned)(g >> 32));
            out_i[(size_t)qi * KSEL + it] = (float)(unsigned)(g & 0xFFFFFFFFu);
        }
        if (pmin == g) {            // unique winner rescans its registers
#pragma unroll
            for (int s = 0; s < 16; ++s) if (k[s] == g) k[s] = ~0ull;
            pmin = ~0ull;
#pragma unroll
            for (int s = 0; s < 16; ++s) pmin = k[s] < pmin ? k[s] : pmin;
        }
    }
}

extern "C" void kernel_launch(void* const* d_in, const int* in_sizes, int n_in,
                              void* d_out, int out_size, void* d_ws, size_t ws_size,
                              hipStream_t stream) {
    const float* x = (const float*)d_in[0];    // anchor_x [8192, 64] fp32
    float* sq = (float*)d_ws;                                        // 32 KB
    unsigned long long* tau0 =
        (unsigned long long*)((char*)d_ws + 32768);                  // 64 KB
    unsigned int* cnt = (unsigned int*)((char*)d_ws + 98304);        // 32 KB
    unsigned long long* lists =
        (unsigned long long*)((char*)d_ws + 131072);                 // 66.8 MB
    float* out_d = (float*)d_out;              // [8160, 32] distances
    float* out_i = out_d + (size_t)NQ * KSEL;  // [8160, 32] indices (as fp32)

    norms_kernel<<<NROWS / 256, 256, 0, stream>>>(x, sq);
    pass1_kernel<<<NQ, 64, 0, stream>>>(x, sq, tau0, cnt, lists);
    dim3 g2(128, (NROWS - P1LEN) / 128);       // (query tile, candidate tile)
    pass2_kernel<<<g2, 256, 0, stream>>>(x, sq, tau0, cnt, lists);
    merge_kernel<<<NQ, 64, 0, stream>>>(lists, cnt, out_d, out_i);
}